// Round 9
// baseline (98.626 us; speedup 1.0000x reference)
//
#include <hip/hip_runtime.h>
#include <hip/hip_bf16.h>
#include <stdint.h>

#define S_LEN 2048
#define BATCH 4
#define HID 1024
#define M_ROWS (BATCH * S_LEN)   // 8192

typedef __attribute__((ext_vector_type(8))) short short8;
typedef __attribute__((ext_vector_type(4))) float f32x4;

__device__ __forceinline__ void gload_lds16(const void* g, void* l) {
  __builtin_amdgcn_global_load_lds(
      (const __attribute__((address_space(1))) unsigned int*)g,
      (__attribute__((address_space(3))) unsigned int*)l, 16, 0, 0);
}

template <int N>
__device__ __forceinline__ void wait_vm() {
  if constexpr (N == 0)
    asm volatile("s_waitcnt vmcnt(0)" ::: "memory");
  else
    asm volatile("s_waitcnt vmcnt(4)" ::: "memory");
}

#define CFENCE asm volatile("" ::: "memory")
#define BAR_PRE do { CFENCE; __builtin_amdgcn_s_barrier();                    \
    asm volatile("s_waitcnt lgkmcnt(0)" ::: "memory"); } while (0)
#define BAR_POST do { CFENCE; __builtin_amdgcn_s_barrier(); CFENCE; } while (0)

// ---------------- fp32 -> bf16 conversion (hs, Wq, Wk) ----------------
__global__ __launch_bounds__(256) void convert_all(
    const float* __restrict__ hs, const float* __restrict__ wq,
    const float* __restrict__ wk,
    __hip_bfloat16* __restrict__ hs_bf, __hip_bfloat16* __restrict__ wq_bf,
    __hip_bfloat16* __restrict__ wk_bf) {
  const int NH = M_ROWS * HID;
  const int NW = HID * HID;
  int idx = (blockIdx.x * blockDim.x + threadIdx.x) * 4;
  const float* src;
  __hip_bfloat16* dst;
  int off;
  if (idx < NH)           { src = hs; dst = hs_bf; off = idx; }
  else if (idx < NH + NW) { src = wq; dst = wq_bf; off = idx - NH; }
  else                    { src = wk; dst = wk_bf; off = idx - NH - NW; }
  float4 v = *reinterpret_cast<const float4*>(src + off);
  __hip_bfloat16 tmp[4];
  tmp[0] = __float2bfloat16(v.x);
  tmp[1] = __float2bfloat16(v.y);
  tmp[2] = __float2bfloat16(v.z);
  tmp[3] = __float2bfloat16(v.w);
  *reinterpret_cast<ushort4*>(dst + off) = *reinterpret_cast<const ushort4*>(tmp);
}

// ========= bf16 256x256 4-phase NT GEMM core (r4/r6-validated) ========
// 512 thr = 8 waves (2Mx4N); per-wave 128x64; BK=64 dbuf LDS 128KB;
// XOR-swizzled 16B slots both sides; counted vmcnt(4); MFMA SWAPPED
// (fb first): acc[m][n] lane layout row = m*16+(l&15),
// col = n*16+(l>>4)*4+r  -> 4 consecutive cols/lane = vector stores.
template <int NT>
__device__ __forceinline__ void gemm_core_bf(
    const __hip_bfloat16* __restrict__ A, const __hip_bfloat16* __restrict__ B,
    const int lda, const int ldb, __hip_bfloat16* lds, f32x4 acc[8][4]) {
  const int t = threadIdx.x;
  const int wid = t >> 6;
  const int l = t & 63;
  const int lr = l & 15;
  const int lk = l >> 4;
  const int wr = wid >> 2;
  const int wc = wid & 3;
  const int trow = t >> 3;
  const int tslot = (t & 7) ^ (trow & 7);
  const int rsx = lr & 7;

  __hip_bfloat16* const A0 = lds;
  __hip_bfloat16* const A1 = lds + 16384;
  __hip_bfloat16* const B0 = lds + 32768;
  __hip_bfloat16* const B1 = lds + 49152;

  short8 fa[4][2], fb[4][2];

#define STAGE_U(lb, gb, ld, half, kt) do {                                    \
    gload_lds16((gb) + (size_t)((half)*128 + 0  + trow) * (ld) + (kt)*64 +    \
                    tslot * 8,                                                \
                (lb) + ((half)*128 + 0) * 64 + wid * 512);                    \
    gload_lds16((gb) + (size_t)((half)*128 + 64 + trow) * (ld) + (kt)*64 +    \
                    tslot * 8,                                                \
                (lb) + ((half)*128 + 64) * 64 + wid * 512);                   \
  } while (0)

#define LDA_H(mh, Ac) do {                                                    \
    _Pragma("unroll") for (int m = 0; m < 4; ++m)                             \
    _Pragma("unroll") for (int kk = 0; kk < 2; ++kk)                          \
      fa[m][kk] = *reinterpret_cast<const short8*>(                           \
          (Ac) + (wr * 128 + (mh)*64 + m * 16 + lr) * 64 +                    \
          (((kk * 4 + lk) ^ rsx) * 8));                                       \
  } while (0)

#define LDB_H(nh, Bc) do {                                                    \
    _Pragma("unroll") for (int n = 0; n < 2; ++n)                             \
    _Pragma("unroll") for (int kk = 0; kk < 2; ++kk)                          \
      fb[(nh)*2 + n][kk] = *reinterpret_cast<const short8*>(                  \
          (Bc) + (wc * 64 + (nh)*32 + n * 16 + lr) * 64 +                     \
          (((kk * 4 + lk) ^ rsx) * 8));                                       \
  } while (0)

#define MFMA_Q(mh, nh) do {                                                   \
    __builtin_amdgcn_s_setprio(1);                                            \
    _Pragma("unroll") for (int m = 0; m < 4; ++m)                             \
    _Pragma("unroll") for (int n = 0; n < 2; ++n)                             \
    _Pragma("unroll") for (int kk = 0; kk < 2; ++kk)                          \
      acc[(mh)*4 + m][(nh)*2 + n] = __builtin_amdgcn_mfma_f32_16x16x32_bf16(  \
          fb[(nh)*2 + n][kk], fa[m][kk], acc[(mh)*4 + m][(nh)*2 + n],         \
          0, 0, 0);                                                           \
    __builtin_amdgcn_s_setprio(0);                                            \
  } while (0)

  STAGE_U(A0, A, lda, 0, 0); STAGE_U(A0, A, lda, 1, 0);
  STAGE_U(B0, B, ldb, 0, 0); STAGE_U(B0, B, ldb, 1, 0);
  STAGE_U(B1, B, ldb, 0, 1); STAGE_U(B1, B, ldb, 1, 1);
  wait_vm<4>();
  __builtin_amdgcn_s_barrier();
  CFENCE;

#pragma unroll 2
  for (int tt = 0; tt < NT; ++tt) {
    const int cur = tt & 1;
    __hip_bfloat16* const Ac = cur ? A1 : A0;
    __hip_bfloat16* const An = cur ? A0 : A1;
    __hip_bfloat16* const Bc = cur ? B1 : B0;
    LDA_H(0, Ac); LDB_H(0, Bc);
    if (tt + 1 < NT) STAGE_U(An, A, lda, 0, tt + 1);
    BAR_PRE; MFMA_Q(0, 0); BAR_POST;
    LDB_H(1, Bc);
    if (tt + 1 < NT) STAGE_U(An, A, lda, 1, tt + 1);
    BAR_PRE; MFMA_Q(0, 1); BAR_POST;
    LDA_H(1, Ac);
    if (tt + 2 < NT) STAGE_U(Bc, B, ldb, 0, tt + 2);
    BAR_PRE; MFMA_Q(1, 1); BAR_POST;
    if (tt + 2 < NT) STAGE_U(Bc, B, ldb, 1, tt + 2);
    BAR_PRE; MFMA_Q(1, 0);
    if (tt + 2 < NT) wait_vm<4>(); else wait_vm<0>();
    BAR_POST;
  }
#undef STAGE_U
#undef LDA_H
#undef LDB_H
#undef MFMA_Q
}

// ------ Q/K projection: X @ W^T + b -> bf16 (vectorized epilogue) ------
// 1-D grid 256, XCD swizzle: xcd owns 4 consecutive bm panels.
__global__ __launch_bounds__(512, 2) void proj_gemm(
    const __hip_bfloat16* __restrict__ X,
    const __hip_bfloat16* __restrict__ Wq, const float* __restrict__ bq,
    const __hip_bfloat16* __restrict__ Wk, const float* __restrict__ bk,
    __hip_bfloat16* __restrict__ Qo, __hip_bfloat16* __restrict__ Ko) {
  extern __shared__ char smem[];
  __hip_bfloat16* lds = reinterpret_cast<__hip_bfloat16*>(smem);
  const int bid = blockIdx.x;
  const int xcd = bid & 7, s = bid >> 3;
  const int bm = xcd * 4 + (s & 3);
  const int bn8 = s >> 2;
  const int z = bn8 >> 2;
  const int bn = bn8 & 3;

  const __hip_bfloat16* W = z ? Wk : Wq;
  const float* bias = z ? bk : bq;
  __hip_bfloat16* Out = z ? Ko : Qo;

  f32x4 acc[8][4];
#pragma unroll
  for (int m = 0; m < 8; ++m)
#pragma unroll
    for (int n = 0; n < 4; ++n) acc[m][n] = (f32x4){0.f, 0.f, 0.f, 0.f};

  gemm_core_bf<HID / 64>(X + (size_t)bm * 256 * HID,
                         W + (size_t)bn * 256 * HID, HID, HID, lds, acc);

  const int t = threadIdx.x, wid = t >> 6, l = t & 63;
  const int wr = wid >> 2, wc = wid & 3;
  const int lr = l & 15, lg = l >> 4;
#pragma unroll
  for (int m = 0; m < 8; ++m) {
    const int row = bm * 256 + wr * 128 + m * 16 + lr;
#pragma unroll
    for (int n = 0; n < 4; ++n) {
      const int col0 = bn * 256 + wc * 64 + n * 16 + lg * 4;
      float4 bb = *reinterpret_cast<const float4*>(&bias[col0]);
      f32x4 a = acc[m][n];
      __hip_bfloat16 tmp[4] = {
          __float2bfloat16(a[0] + bb.x), __float2bfloat16(a[1] + bb.y),
          __float2bfloat16(a[2] + bb.z), __float2bfloat16(a[3] + bb.w)};
      *reinterpret_cast<ushort4*>(&Out[(size_t)row * HID + col0]) =
          *reinterpret_cast<const ushort4*>(tmp);
    }
  }
}

// ---- scores: 128x128 tiles, BK=64, 256 thr (4 waves 2x2), 64KB LDS ----
// -> 2 resident blocks/CU: cross-block overlap hides barriers + the
// terminal fp32 write burst. fb[4][2] keeps ALL n-frags live (c3 reuses
// fb[0..1] from c0 — the r8 bug was collapsing this to fb[2][2]).
// grid 1024; XCD chunk: xcd owns 4bm x 8bn per batch (bijective).
__global__ __launch_bounds__(256, 2) void scores_gemm(
    const __hip_bfloat16* __restrict__ Q, const __hip_bfloat16* __restrict__ Km,
    const float* __restrict__ mask, float* __restrict__ out) {
  extern __shared__ char smem[];
  __hip_bfloat16* lds = reinterpret_cast<__hip_bfloat16*>(smem);
  const int bid = blockIdx.x;
  const int xcd = bid & 7, slot = bid >> 3;      // slot 0..127
  const int b = slot >> 5, sub = slot & 31;      // b 0..3, sub 0..31
  const int bm = (xcd & 3) * 4 + (sub >> 3);     // 0..15
  const int bn = (xcd >> 2) * 8 + (sub & 7);     // 0..15

  const __hip_bfloat16* A = Q + ((size_t)b * S_LEN + bm * 128) * HID;
  const __hip_bfloat16* B = Km + ((size_t)b * S_LEN + bn * 128) * HID;

  const int t = threadIdx.x;
  const int wid = t >> 6;
  const int l = t & 63;
  const int lr = l & 15;
  const int lk = l >> 4;
  const int wr = wid >> 1;      // wave row 0..1 (64 rows each)
  const int wc = wid & 1;       // wave col 0..1 (64 cols each)
  const int trow = t >> 3;      // 0..31 (rows per issue)
  const int tslot = (t & 7) ^ (trow & 7);
  const int rsx = lr & 7;

  __hip_bfloat16* const A0 = lds;
  __hip_bfloat16* const A1 = lds + 8192;
  __hip_bfloat16* const B0 = lds + 16384;
  __hip_bfloat16* const B1 = lds + 24576;

  f32x4 acc[4][4];
#pragma unroll
  for (int m = 0; m < 4; ++m)
#pragma unroll
    for (int n = 0; n < 4; ++n) acc[m][n] = (f32x4){0.f, 0.f, 0.f, 0.f};

  short8 fa[2][2], fb[4][2];

// one STAGE half = 64 rows = 2 gload_lds issues (32 rows each)
#define STAGE_S(lb, gb, half, kt) do {                                        \
    gload_lds16((gb) + (size_t)((half)*64 + 0  + trow) * HID + (kt)*64 +      \
                    tslot * 8,                                                \
                (lb) + (half)*4096 + wid * 512);                              \
    gload_lds16((gb) + (size_t)((half)*64 + 32 + trow) * HID + (kt)*64 +      \
                    tslot * 8,                                                \
                (lb) + (half)*4096 + 2048 + wid * 512);                       \
  } while (0)

#define LDA_S(mh, Ac) do {                                                    \
    _Pragma("unroll") for (int m = 0; m < 2; ++m)                             \
    _Pragma("unroll") for (int kk = 0; kk < 2; ++kk)                          \
      fa[m][kk] = *reinterpret_cast<const short8*>(                           \
          (Ac) + (wr * 64 + (mh)*32 + m * 16 + lr) * 64 +                     \
          (((kk * 4 + lk) ^ rsx) * 8));                                       \
  } while (0)

#define LDB_S(nh, Bc) do {                                                    \
    _Pragma("unroll") for (int n = 0; n < 2; ++n)                             \
    _Pragma("unroll") for (int kk = 0; kk < 2; ++kk)                          \
      fb[(nh)*2 + n][kk] = *reinterpret_cast<const short8*>(                  \
          (Bc) + (wc * 64 + (nh)*32 + n * 16 + lr) * 64 +                     \
          (((kk * 4 + lk) ^ rsx) * 8));                                       \
  } while (0)

#define MFMA_S(mh, nh) do {                                                   \
    __builtin_amdgcn_s_setprio(1);                                            \
    _Pragma("unroll") for (int m = 0; m < 2; ++m)                             \
    _Pragma("unroll") for (int n = 0; n < 2; ++n)                             \
    _Pragma("unroll") for (int kk = 0; kk < 2; ++kk)                          \
      acc[(mh)*2 + m][(nh)*2 + n] = __builtin_amdgcn_mfma_f32_16x16x32_bf16(  \
          fb[(nh)*2 + n][kk], fa[m][kk], acc[(mh)*2 + m][(nh)*2 + n],         \
          0, 0, 0);                                                           \
    __builtin_amdgcn_s_setprio(0);                                            \
  } while (0)

  constexpr int NT = HID / 64;   // 16
  // prologue: tile0 fully, tile1 B (12 issues; drain 8 -> vmcnt(4))
  STAGE_S(A0, A, 0, 0); STAGE_S(A0, A, 1, 0);
  STAGE_S(B0, B, 0, 0); STAGE_S(B0, B, 1, 0);
  STAGE_S(B1, B, 0, 1); STAGE_S(B1, B, 1, 1);
  wait_vm<4>();
  __builtin_amdgcn_s_barrier();
  CFENCE;

#pragma unroll 2
  for (int tt = 0; tt < NT; ++tt) {
    const int cur = tt & 1;
    __hip_bfloat16* const Ac = cur ? A1 : A0;
    __hip_bfloat16* const An = cur ? A0 : A1;
    __hip_bfloat16* const Bc = cur ? B1 : B0;
    // c0: (m0-1, n0-1); stage A-h0(t+1)
    LDA_S(0, Ac); LDB_S(0, Bc);
    if (tt + 1 < NT) STAGE_S(An, A, 0, tt + 1);
    BAR_PRE; MFMA_S(0, 0); BAR_POST;
    // c1: (m0-1, n2-3); stage A-h1(t+1)
    LDB_S(1, Bc);
    if (tt + 1 < NT) STAGE_S(An, A, 1, tt + 1);
    BAR_PRE; MFMA_S(0, 1); BAR_POST;
    // c2: (m2-3, n2-3); stage B-h0(t+2) (same-parity buffer, reads done @c1)
    LDA_S(1, Ac);
    if (tt + 2 < NT) STAGE_S(Bc, B, 0, tt + 2);
    BAR_PRE; MFMA_S(1, 1); BAR_POST;
    // c3: (m2-3, n0-1) reusing fb[0..1] from c0; stage B-h1(t+2); drain
    if (tt + 2 < NT) STAGE_S(Bc, B, 1, tt + 2);
    BAR_PRE; MFMA_S(1, 0);
    if (tt + 2 < NT) wait_vm<4>(); else wait_vm<0>();
    BAR_POST;
  }
#undef STAGE_S
#undef LDA_S
#undef LDB_S
#undef MFMA_S

  const int lg = l >> 4;
  const float inv = 1.0f / 128.0f;   // 1/sqrt(64) * 1/16 heads
#pragma unroll
  for (int m = 0; m < 4; ++m) {
    const int row = bm * 128 + wr * 64 + m * 16 + lr;
    const float mr = mask[b * S_LEN + row] * inv;
#pragma unroll
    for (int n = 0; n < 4; ++n) {
      const int col0 = bn * 128 + wc * 64 + n * 16 + lg * 4;
      float4 mcv = *reinterpret_cast<const float4*>(&mask[b * S_LEN + col0]);
      f32x4 a = acc[m][n];
      float4 o = {a[0] * mr * mcv.x, a[1] * mr * mcv.y,
                  a[2] * mr * mcv.z, a[3] * mr * mcv.w};
      *reinterpret_cast<float4*>(
          &out[(size_t)b * S_LEN * S_LEN + (size_t)row * S_LEN + col0]) = o;
    }
  }
}

extern "C" void kernel_launch(void* const* d_in, const int* in_sizes, int n_in,
                              void* d_out, int out_size, void* d_ws,
                              size_t ws_size, hipStream_t stream) {
  const float* hs   = (const float*)d_in[0];
  const float* mask = (const float*)d_in[1];
  const float* Wq   = (const float*)d_in[2];
  const float* bq   = (const float*)d_in[3];
  const float* Wk   = (const float*)d_in[4];
  const float* bk   = (const float*)d_in[5];
  float* out = (float*)d_out;

  char* ws = (char*)d_ws;
  __hip_bfloat16* hs_bf = (__hip_bfloat16*)(ws);                 // 16 MB
  __hip_bfloat16* wq_bf = (__hip_bfloat16*)(ws + 16777216);      //  2 MB
  __hip_bfloat16* wk_bf = (__hip_bfloat16*)(ws + 18874368);      //  2 MB
  __hip_bfloat16* q_bf  = (__hip_bfloat16*)(ws + 20971520);      // 16 MB
  __hip_bfloat16* k_bf  = (__hip_bfloat16*)(ws + 37748736);      // 16 MB

  (void)hipFuncSetAttribute((const void*)proj_gemm,
                            hipFuncAttributeMaxDynamicSharedMemorySize, 131072);
  (void)hipFuncSetAttribute((const void*)scores_gemm,
                            hipFuncAttributeMaxDynamicSharedMemorySize, 65536);

  hipLaunchKernelGGL(convert_all, dim3(10240), dim3(256), 0, stream,
                     hs, Wq, Wk, hs_bf, wq_bf, wk_bf);
  hipLaunchKernelGGL(proj_gemm, dim3(256), dim3(512), 131072, stream,
                     hs_bf, wq_bf, bq, wk_bf, bk, q_bf, k_bf);
  hipLaunchKernelGGL(scores_gemm, dim3(1024), dim3(256), 65536, stream,
                     q_bf, k_bf, mask, out);
}